// Round 4
// baseline (89.180 us; speedup 1.0000x reference)
//
#include <hip/hip_runtime.h>
#include <hip/hip_bf16.h>

typedef __attribute__((ext_vector_type(8))) short short8v;
typedef __attribute__((ext_vector_type(4))) float float4v;

// Problem constants
#define NB 64
#define NN 2048
#define ED 128
#define CHUNK 64
#define NCHUNK (NN/CHUNK)     // 32
#define GRID_C (NB*NCHUNK)    // 2048

// workspace layout (float offsets)
#define WS_WEFF  0                  // 64 (weff[63], [63]=0)
#define WS_BEFF  64                 // 1
#define WS_ACC   65                 // float accumulator
#define WS_CNT   66                 // int completion counter
#define WS_SHIGH 128                // 64
#define WS_QTERM 192                // 64*64  (qterm + b3 folded)
#define WS_QPRE  (192+4096)         // 64*128
#define WS_BPACK (WS_QPRE+8192)     // bf16[16384] = 4096 floats, 16B aligned

static __device__ __forceinline__ unsigned int packbf2(float a, float b) {
    __hip_bfloat162 h = __float22bfloat162_rn(make_float2(a, b));
    return *(unsigned int*)&h;
}

// ---------------- Kernel P: blocks 0..NB-1 per-batch precompute; block NB: weff/beff + bpack ----------------
__global__ __launch_bounds__(64) void k_prep(
    const float* __restrict__ top_user, const float* __restrict__ question,
    const float* __restrict__ W1, const float* __restrict__ b1,
    const float* __restrict__ W2, const float* __restrict__ b2,
    const float* __restrict__ W3, const float* __restrict__ b3,
    const float* __restrict__ fw1, const float* __restrict__ fb1,
    const float* __restrict__ fw2, const float* __restrict__ fb2,
    const float* __restrict__ fw3, const float* __restrict__ fb3,
    float* __restrict__ ws)
{
    const int lane = threadIdx.x;
    const int blk = blockIdx.x;
    __shared__ float g[16];
    __shared__ float w3s[192];
    // stage W3 into LDS (kills the divergent-global-load latency chain)
    w3s[lane] = W3[lane];
    w3s[64 + lane] = W3[64 + lane];
    w3s[128 + lane] = W3[128 + lane];
    if (lane < 16) {
        float s = 0.f;
        #pragma unroll
        for (int i = 0; i < 16; ++i) s += fw3[i] * fw2[i*16 + lane];
        g[lane] = s;
    }
    __syncthreads();

    if (blk == NB) {
        // reset reduction state for this launch
        if (lane == 0) {
            ws[WS_ACC] = 0.f;
            *(int*)&ws[WS_CNT] = 0;
        }
        // weff / beff
        float wv = 0.f;
        if (lane < 63) {
            #pragma unroll
            for (int k = 0; k < 16; ++k) wv += g[k] * fw1[k*63 + lane];
        }
        ws[WS_WEFF + lane] = wv;
        if (lane == 0) {
            float be = fb3[0];
            #pragma unroll
            for (int i = 0; i < 16; ++i) be += fw3[i] * fb2[i];
            #pragma unroll
            for (int k = 0; k < 16; ++k) be += g[k] * fb1[k];
            ws[WS_BEFF] = be;
        }
        // Toeplitz B-pack in fragment order, all reads from LDS:
        // bp[((kt*4+nt)*64+lane)*8+idx] = B[kt*32+8*(lane>>4)+idx][nt*16+(lane&15)]
        __hip_bfloat16* bp = (__hip_bfloat16*)(ws + WS_BPACK);
        const int g8 = (lane >> 4) * 8, li = lane & 15;
        #pragma unroll
        for (int kt = 0; kt < 8; ++kt) {
            #pragma unroll
            for (int nt = 0; nt < 4; ++nt) {
                const int tt = nt*16 + li;
                #pragma unroll
                for (int idx = 0; idx < 8; ++idx) {
                    const int k = kt*32 + g8 + idx;
                    const int j = k - tt;
                    const int k2 = k - 128, j2 = k2 - tt;
                    const bool v0 = (tt < 63) && (k < 126) && (j >= 0) && (j < 64);
                    const bool v2 = (tt < 63) && (k2 >= 0) && (k2 < 126) && (j2 >= 0) && (j2 < 64);
                    float v = (v0 ? w3s[j & 63] : 0.f) + (v2 ? w3s[128 + (j2 & 63)] : 0.f);
                    bp[((kt*4 + nt)*64 + lane)*8 + idx] = __float2bfloat16(v);
                }
            }
        }
        return;
    }

    // per-batch precompute (weff/beff recomputed locally)
    float wv = 0.f;
    if (lane < 63) {
        #pragma unroll
        for (int k = 0; k < 16; ++k) wv += g[k] * fw1[k*63 + lane];
    }
    float be = fb3[0];
    #pragma unroll
    for (int i = 0; i < 16; ++i) be += fw3[i] * fb2[i];
    #pragma unroll
    for (int k = 0; k < 16; ++k) be += g[k] * fb1[k];

    __shared__ float q[132], tu[132], c1q[128], qt[64];
    __shared__ float4 D4[64];
    const int b = blk;
    ((float2*)q)[lane]  = ((const float2*)(question + b*ED))[lane];
    ((float2*)tu)[lane] = ((const float2*)(top_user + b*ED))[lane];
    if (lane == 63) {
        q[128]=0.f; q[129]=0.f; q[130]=0.f; q[131]=0.f;
        tu[128]=0.f; tu[129]=0.f; tu[130]=0.f; tu[131]=0.f;
    }
    __syncthreads();
    const float w10=W1[0], w11=W1[1], w12=W1[2];
    const float w20=W2[0], w21=W2[1], w22=W2[2];
    const float w23=W2[3], w24=W2[4], w25=W2[5];
    const float b1v=b1[0], b2v=b2[0], b3v=b3[0];
    const int i = 2*lane;
    float c1qa = fmaxf(b1v + w10*q[i]   + w11*q[i+1] + w12*q[i+2], 0.f);
    float c1qb = fmaxf(b1v + w10*q[i+1] + w11*q[i+2] + w12*q[i+3], 0.f);
    float qpa  = w23*q[i]   + w24*q[i+1] + w25*q[i+2];
    float qpb  = w23*q[i+1] + w24*q[i+2] + w25*q[i+3];
    float c1ta = fmaxf(b1v + w10*tu[i]   + w11*tu[i+1] + w12*tu[i+2], 0.f);
    float c1tb = fmaxf(b1v + w10*tu[i+1] + w11*tu[i+2] + w12*tu[i+3], 0.f);
    float c2a  = fmaxf(b2v + w20*tu[i]   + w21*tu[i+1] + w22*tu[i+2] + qpa, 0.f);
    float c2b  = fmaxf(b2v + w20*tu[i+1] + w21*tu[i+2] + w22*tu[i+3] + qpb, 0.f);
    if (lane == 63) { c1qa=0.f; c1qb=0.f; qpa=0.f; qpb=0.f; c1ta=0.f; c1tb=0.f; c2a=0.f; c2b=0.f; }
    c1q[i] = c1qa; c1q[i+1] = c1qb;
    ws[WS_QPRE + b*128 + i]     = qpa;
    ws[WS_QPRE + b*128 + i + 1] = qpb;
    D4[lane] = make_float4(c1ta, c2a, c1tb, c2b);
    __syncthreads();
    float qtv = 0.f;
    if (lane < 63) {
        #pragma unroll
        for (int j = 0; j < 64; ++j) qtv += w3s[64 + j] * c1q[lane + j];
    }
    qt[lane] = qtv;
    ws[WS_QTERM + b*64 + lane] = qtv + b3v;   // fold b3 for GEMM epilogue
    __syncthreads();
    float acc0 = b3v + qt[lane];
    float acc1 = 0.f;
    const float2* D2 = (const float2*)D4;
    #pragma unroll
    for (int j = 0; j < 64; ++j) {
        const float2 d = D2[lane + j];
        acc0 = fmaf(w3s[j],       d.x, acc0);
        acc1 = fmaf(w3s[128 + j], d.y, acc1);
    }
    float v = wv * fmaxf(acc0 + acc1, 0.f);
    #pragma unroll
    for (int off = 32; off > 0; off >>= 1) v += __shfl_xor(v, off, 64);
    if (lane == 0) ws[WS_SHIGH + b] = v + be;
}

// ---------------- Kernel C: pairs via MFMA GEMM (B in regs) + fused final reduce ----------------
__global__ __launch_bounds__(256) void k_pairs(
    const float* __restrict__ users, const int* __restrict__ uids,
    float* __restrict__ ws, float* __restrict__ out,
    const float* __restrict__ W1, const float* __restrict__ b1,
    const float* __restrict__ W2, const float* __restrict__ b2)
{
    // X: 64 pairs x 264 bf16 (k 0..255 valid), row stride 132 dwords
    __shared__ __align__(16) unsigned int X[64][132];   // 33792 B
    __shared__ float pscore[2][64];
    const int tid = threadIdx.x;
    const int w = tid >> 6, lane = tid & 63;
    const int bid = blockIdx.x;
    const int b = bid >> 5;
    const int chunk = bid & 31;
    const int base = b*NN + chunk*CHUNK;

    float blocksum = -1.f;   // <0 => skip float atomic

    // prefix property: uids nonzero exactly for n < length
    if (uids[base] != 0) {
        const int g = lane >> 4, li = lane & 15;
        const int nhalf = w >> 1;            // tap half
        const int mbase = (w & 1) * 32;      // pair half

        // B fragments from global (32KB, L2/L3-resident, shared by all blocks)
        const __hip_bfloat16* bp = (const __hip_bfloat16*)(ws + WS_BPACK);
        short8v bfr0[8], bfr1[8];
        #pragma unroll
        for (int kt = 0; kt < 8; ++kt) {
            bfr0[kt] = *(const short8v*)(bp + (((kt*4 + nhalf*2 + 0)*64 + lane) << 3));
            bfr1[kt] = *(const short8v*)(bp + (((kt*4 + nhalf*2 + 1)*64 + lane) << 3));
        }

        const int t0 = nhalf*32 + li, t1 = t0 + 16;
        const float wf0 = ws[WS_WEFF + t0], wf1 = ws[WS_WEFF + t1];
        const float qt0 = ws[WS_QTERM + b*64 + t0], qt1 = ws[WS_QTERM + b*64 + t1];
        const float shigh = ws[WS_SHIGH + b], beff = ws[WS_BEFF];

        // X-prep: 2 rows/pass, float4 loads, neighbor taps via shfl
        const float w10=W1[0], w11=W1[1], w12=W1[2];
        const float w20=W2[0], w21=W2[1], w22=W2[2];
        const float b1v=b1[0], b2v=b2[0];
        const int h = lane >> 5, j = lane & 31;
        const float4 qp4 = *(const float4*)&ws[WS_QPRE + b*128 + 4*j];
        const int r0 = w * 16;
        #pragma unroll
        for (int pass = 0; pass < 8; ++pass) {
            const int r = r0 + pass*2 + h;
            const float4 uu = *(const float4*)(users + (size_t)(base + r)*ED + 4*j);
            const float nx = __shfl(uu.x, (lane + 1) & 63, 64);
            const float ny = __shfl(uu.y, (lane + 1) & 63, 64);
            float c10 = fmaxf(b1v + w10*uu.x + w11*uu.y + w12*uu.z, 0.f);
            float c11 = fmaxf(b1v + w10*uu.y + w11*uu.z + w12*uu.w, 0.f);
            float c12 = fmaxf(b1v + w10*uu.z + w11*uu.w + w12*nx  , 0.f);
            float c13 = fmaxf(b1v + w10*uu.w + w11*nx   + w12*ny  , 0.f);
            float c20 = fmaxf(b2v + w20*uu.x + w21*uu.y + w22*uu.z + qp4.x, 0.f);
            float c21 = fmaxf(b2v + w20*uu.y + w21*uu.z + w22*uu.w + qp4.y, 0.f);
            float c22 = fmaxf(b2v + w20*uu.z + w21*uu.w + w22*nx   + qp4.z, 0.f);
            float c23 = fmaxf(b2v + w20*uu.w + w21*nx   + w22*ny   + qp4.w, 0.f);
            if (j == 31) { c12 = 0.f; c13 = 0.f; c22 = 0.f; c23 = 0.f; }   // conv pads
            uint2 v1; v1.x = packbf2(c10, c11); v1.y = packbf2(c12, c13);
            uint2 v2; v2.x = packbf2(c20, c21); v2.y = packbf2(c22, c23);
            *(uint2*)&X[r][2*j]      = v1;
            *(uint2*)&X[r][64 + 2*j] = v2;
        }
        __syncthreads();

        // GEMM: wave quadrant = 32 pairs x 32 taps, K=256
        float4v acc00 = {0.f,0.f,0.f,0.f}, acc01 = {0.f,0.f,0.f,0.f};
        float4v acc10 = {0.f,0.f,0.f,0.f}, acc11 = {0.f,0.f,0.f,0.f};
        const char* Xb = (const char*)&X[0][0];
        #pragma unroll
        for (int kt = 0; kt < 8; ++kt) {
            const short8v a0 = *(const short8v*)(Xb + (mbase + li)*528      + kt*64 + g*16);
            const short8v a1 = *(const short8v*)(Xb + (mbase + 16 + li)*528 + kt*64 + g*16);
            acc00 = __builtin_amdgcn_mfma_f32_16x16x32_bf16(a0, bfr0[kt], acc00, 0, 0, 0);
            acc01 = __builtin_amdgcn_mfma_f32_16x16x32_bf16(a0, bfr1[kt], acc01, 0, 0, 0);
            acc10 = __builtin_amdgcn_mfma_f32_16x16x32_bf16(a1, bfr0[kt], acc10, 0, 0, 0);
            acc11 = __builtin_amdgcn_mfma_f32_16x16x32_bf16(a1, bfr1[kt], acc11, 0, 0, 0);
        }

        // epilogue: per-pair partials over this wave's 32 taps
        #pragma unroll
        for (int mi = 0; mi < 2; ++mi) {
            #pragma unroll
            for (int reg = 0; reg < 4; ++reg) {
                const float a0v = mi ? acc10[reg] : acc00[reg];
                const float a1v = mi ? acc11[reg] : acc01[reg];
                float v = wf0 * fmaxf(a0v + qt0, 0.f) + wf1 * fmaxf(a1v + qt1, 0.f);
                v += __shfl_xor(v, 1, 64);
                v += __shfl_xor(v, 2, 64);
                v += __shfl_xor(v, 4, 64);
                v += __shfl_xor(v, 8, 64);
                if (li == 0) pscore[nhalf][mbase + mi*16 + g*4 + reg] = v;
            }
        }
        __syncthreads();

        if (w == 0) {
            const float d = pscore[0][lane] + pscore[1][lane] + beff - shigh;
            float val = (uids[base + lane] != 0) ? 1.f / (1.f + __expf(-d)) : 0.f;
            #pragma unroll
            for (int off = 32; off > 0; off >>= 1) val += __shfl_xor(val, off, 64);
            blocksum = val;   // lane 0 holds the block sum
        }
    }

    // fused reduction: float atomic accumulate + completion counter; last block writes out
    if (tid == 0) {
        if (blocksum >= 0.f) atomicAdd(&ws[WS_ACC], blocksum);
        __threadfence();
        const int prev = atomicAdd((int*)&ws[WS_CNT], 1);
        if (prev == GRID_C - 1) {
            out[0] = atomicAdd(&ws[WS_ACC], 0.f);   // coherent read
        }
    }
}

extern "C" void kernel_launch(void* const* d_in, const int* in_sizes, int n_in,
                              void* d_out, int out_size, void* d_ws, size_t ws_size,
                              hipStream_t stream)
{
    const float* users    = (const float*)d_in[0];
    const float* top_user = (const float*)d_in[1];
    const float* question = (const float*)d_in[2];
    const int*   uids     = (const int*)d_in[3];
    const float* W1  = (const float*)d_in[4];
    const float* b1  = (const float*)d_in[5];
    const float* W2  = (const float*)d_in[6];
    const float* b2  = (const float*)d_in[7];
    const float* W3  = (const float*)d_in[8];
    const float* b3  = (const float*)d_in[9];
    const float* fw1 = (const float*)d_in[10];
    const float* fb1 = (const float*)d_in[11];
    const float* fw2 = (const float*)d_in[12];
    const float* fb2 = (const float*)d_in[13];
    const float* fw3 = (const float*)d_in[14];
    const float* fb3 = (const float*)d_in[15];
    float* ws  = (float*)d_ws;
    float* out = (float*)d_out;

    hipLaunchKernelGGL(k_prep, dim3(NB + 1), dim3(64), 0, stream,
                       top_user, question, W1, b1, W2, b2, W3, b3,
                       fw1, fb1, fw2, fb2, fw3, fb3, ws);
    hipLaunchKernelGGL(k_pairs, dim3(GRID_C), dim3(256), 0, stream,
                       users, uids, ws, out, W1, b1, W2, b2);
}

// Round 5
// 42.552 us; speedup vs baseline: 2.0958x; 2.0958x over previous
//
#include <hip/hip_runtime.h>
#include <hip/hip_bf16.h>

typedef __attribute__((ext_vector_type(8))) short short8v;
typedef __attribute__((ext_vector_type(4))) float float4v;

// Problem constants
#define NB 64
#define NN 2048
#define ED 128
#define CHUNK 64
#define NCHUNK (NN/CHUNK)     // 32
#define GRID_C (NB*NCHUNK)    // 2048

// workspace layout (float offsets)
#define WS_WEFF  0                  // 64 (weff[63], [63]=0)
#define WS_BEFF  64                 // 1
#define WS_SHIGH 128                // 64
#define WS_QTERM 192                // 64*64  (qterm + b3 folded)
#define WS_QPRE  (192+4096)         // 64*128
#define WS_PART  (WS_QPRE+8192)     // 2048
#define WS_BPACK (WS_PART+2048)     // bf16[16384] = 4096 floats, 16B aligned

static __device__ __forceinline__ unsigned int packbf2(float a, float b) {
    __hip_bfloat162 h = __float22bfloat162_rn(make_float2(a, b));
    return *(unsigned int*)&h;
}

// ---------------- Kernel P: blocks 0..NB-1 per-batch precompute; block NB: weff/beff + bpack ----------------
__global__ __launch_bounds__(64) void k_prep(
    const float* __restrict__ top_user, const float* __restrict__ question,
    const float* __restrict__ W1, const float* __restrict__ b1,
    const float* __restrict__ W2, const float* __restrict__ b2,
    const float* __restrict__ W3, const float* __restrict__ b3,
    const float* __restrict__ fw1, const float* __restrict__ fb1,
    const float* __restrict__ fw2, const float* __restrict__ fb2,
    const float* __restrict__ fw3, const float* __restrict__ fb3,
    float* __restrict__ ws)
{
    const int lane = threadIdx.x;
    const int blk = blockIdx.x;
    __shared__ float g[16];
    __shared__ float w3s[192];
    // stage W3 into LDS (kills the divergent-global-load latency chain)
    w3s[lane] = W3[lane];
    w3s[64 + lane] = W3[64 + lane];
    w3s[128 + lane] = W3[128 + lane];
    if (lane < 16) {
        float s = 0.f;
        #pragma unroll
        for (int i = 0; i < 16; ++i) s += fw3[i] * fw2[i*16 + lane];
        g[lane] = s;
    }
    __syncthreads();

    if (blk == NB) {
        // weff / beff
        float wv = 0.f;
        if (lane < 63) {
            #pragma unroll
            for (int k = 0; k < 16; ++k) wv += g[k] * fw1[k*63 + lane];
        }
        ws[WS_WEFF + lane] = wv;
        if (lane == 0) {
            float be = fb3[0];
            #pragma unroll
            for (int i = 0; i < 16; ++i) be += fw3[i] * fb2[i];
            #pragma unroll
            for (int k = 0; k < 16; ++k) be += g[k] * fb1[k];
            ws[WS_BEFF] = be;
        }
        // Toeplitz B-pack in fragment order, all reads from LDS:
        // bp[((kt*4+nt)*64+lane)*8+idx] = B[kt*32+8*(lane>>4)+idx][nt*16+(lane&15)]
        __hip_bfloat16* bp = (__hip_bfloat16*)(ws + WS_BPACK);
        const int g8 = (lane >> 4) * 8, li = lane & 15;
        #pragma unroll
        for (int kt = 0; kt < 8; ++kt) {
            #pragma unroll
            for (int nt = 0; nt < 4; ++nt) {
                const int tt = nt*16 + li;
                #pragma unroll
                for (int idx = 0; idx < 8; ++idx) {
                    const int k = kt*32 + g8 + idx;
                    const int j = k - tt;
                    const int k2 = k - 128, j2 = k2 - tt;
                    const bool v0 = (tt < 63) && (k < 126) && (j >= 0) && (j < 64);
                    const bool v2 = (tt < 63) && (k2 >= 0) && (k2 < 126) && (j2 >= 0) && (j2 < 64);
                    float v = (v0 ? w3s[j & 63] : 0.f) + (v2 ? w3s[128 + (j2 & 63)] : 0.f);
                    bp[((kt*4 + nt)*64 + lane)*8 + idx] = __float2bfloat16(v);
                }
            }
        }
        return;
    }

    // per-batch precompute (weff/beff recomputed locally)
    float wv = 0.f;
    if (lane < 63) {
        #pragma unroll
        for (int k = 0; k < 16; ++k) wv += g[k] * fw1[k*63 + lane];
    }
    float be = fb3[0];
    #pragma unroll
    for (int i = 0; i < 16; ++i) be += fw3[i] * fb2[i];
    #pragma unroll
    for (int k = 0; k < 16; ++k) be += g[k] * fb1[k];

    __shared__ float q[132], tu[132], c1q[128], qt[64];
    __shared__ float4 D4[64];
    const int b = blk;
    ((float2*)q)[lane]  = ((const float2*)(question + b*ED))[lane];
    ((float2*)tu)[lane] = ((const float2*)(top_user + b*ED))[lane];
    if (lane == 63) {
        q[128]=0.f; q[129]=0.f; q[130]=0.f; q[131]=0.f;
        tu[128]=0.f; tu[129]=0.f; tu[130]=0.f; tu[131]=0.f;
    }
    __syncthreads();
    const float w10=W1[0], w11=W1[1], w12=W1[2];
    const float w20=W2[0], w21=W2[1], w22=W2[2];
    const float w23=W2[3], w24=W2[4], w25=W2[5];
    const float b1v=b1[0], b2v=b2[0], b3v=b3[0];
    const int i = 2*lane;
    float c1qa = fmaxf(b1v + w10*q[i]   + w11*q[i+1] + w12*q[i+2], 0.f);
    float c1qb = fmaxf(b1v + w10*q[i+1] + w11*q[i+2] + w12*q[i+3], 0.f);
    float qpa  = w23*q[i]   + w24*q[i+1] + w25*q[i+2];
    float qpb  = w23*q[i+1] + w24*q[i+2] + w25*q[i+3];
    float c1ta = fmaxf(b1v + w10*tu[i]   + w11*tu[i+1] + w12*tu[i+2], 0.f);
    float c1tb = fmaxf(b1v + w10*tu[i+1] + w11*tu[i+2] + w12*tu[i+3], 0.f);
    float c2a  = fmaxf(b2v + w20*tu[i]   + w21*tu[i+1] + w22*tu[i+2] + qpa, 0.f);
    float c2b  = fmaxf(b2v + w20*tu[i+1] + w21*tu[i+2] + w22*tu[i+3] + qpb, 0.f);
    if (lane == 63) { c1qa=0.f; c1qb=0.f; qpa=0.f; qpb=0.f; c1ta=0.f; c1tb=0.f; c2a=0.f; c2b=0.f; }
    c1q[i] = c1qa; c1q[i+1] = c1qb;
    ws[WS_QPRE + b*128 + i]     = qpa;
    ws[WS_QPRE + b*128 + i + 1] = qpb;
    D4[lane] = make_float4(c1ta, c2a, c1tb, c2b);
    __syncthreads();
    float qtv = 0.f;
    if (lane < 63) {
        #pragma unroll
        for (int j = 0; j < 64; ++j) qtv += w3s[64 + j] * c1q[lane + j];
    }
    qt[lane] = qtv;
    ws[WS_QTERM + b*64 + lane] = qtv + b3v;   // fold b3 for GEMM epilogue
    __syncthreads();
    float acc0 = b3v + qt[lane];
    float acc1 = 0.f;
    const float2* D2 = (const float2*)D4;
    #pragma unroll
    for (int j = 0; j < 64; ++j) {
        const float2 d = D2[lane + j];
        acc0 = fmaf(w3s[j],       d.x, acc0);
        acc1 = fmaf(w3s[128 + j], d.y, acc1);
    }
    float v = wv * fmaxf(acc0 + acc1, 0.f);
    #pragma unroll
    for (int off = 32; off > 0; off >>= 1) v += __shfl_xor(v, off, 64);
    if (lane == 0) ws[WS_SHIGH + b] = v + be;
}

// ---------------- Kernel C: pairs via MFMA GEMM (B in regs), per-block partial out ----------------
__global__ __launch_bounds__(256) void k_pairs(
    const float* __restrict__ users, const int* __restrict__ uids,
    float* __restrict__ ws,
    const float* __restrict__ W1, const float* __restrict__ b1,
    const float* __restrict__ W2, const float* __restrict__ b2)
{
    // X: 64 pairs x 264 bf16 (k 0..255 valid), row stride 132 dwords
    __shared__ __align__(16) unsigned int X[64][132];   // 33792 B
    __shared__ float pscore[2][64];
    const int tid = threadIdx.x;
    const int w = tid >> 6, lane = tid & 63;
    const int bid = blockIdx.x;
    const int b = bid >> 5;
    const int chunk = bid & 31;
    const int base = b*NN + chunk*CHUNK;

    // prefix property: uids nonzero exactly for n < length
    if (uids[base] == 0) {
        if (tid == 0) ws[WS_PART + bid] = 0.f;
        return;
    }

    const int g = lane >> 4, li = lane & 15;
    const int nhalf = w >> 1;            // tap half
    const int mbase = (w & 1) * 32;      // pair half

    // mask load early (in flight during prep+GEMM)
    const int myuid = (w == 0) ? uids[base + lane] : 1;

    // B fragments from global (32KB, L2/L3-resident, shared by all blocks)
    const __hip_bfloat16* bp = (const __hip_bfloat16*)(ws + WS_BPACK);
    short8v bfr0[8], bfr1[8];
    #pragma unroll
    for (int kt = 0; kt < 8; ++kt) {
        bfr0[kt] = *(const short8v*)(bp + (((kt*4 + nhalf*2 + 0)*64 + lane) << 3));
        bfr1[kt] = *(const short8v*)(bp + (((kt*4 + nhalf*2 + 1)*64 + lane) << 3));
    }

    const int t0 = nhalf*32 + li, t1 = t0 + 16;
    const float wf0 = ws[WS_WEFF + t0], wf1 = ws[WS_WEFF + t1];
    const float qt0 = ws[WS_QTERM + b*64 + t0], qt1 = ws[WS_QTERM + b*64 + t1];
    const float shigh = ws[WS_SHIGH + b], beff = ws[WS_BEFF];

    // X-prep: 2 rows/pass, float4 loads, neighbor taps via shfl
    const float w10=W1[0], w11=W1[1], w12=W1[2];
    const float w20=W2[0], w21=W2[1], w22=W2[2];
    const float b1v=b1[0], b2v=b2[0];
    const int h = lane >> 5, j = lane & 31;
    const float4 qp4 = *(const float4*)&ws[WS_QPRE + b*128 + 4*j];
    const int r0 = w * 16;
    #pragma unroll
    for (int pass = 0; pass < 8; ++pass) {
        const int r = r0 + pass*2 + h;
        const float4 uu = *(const float4*)(users + (size_t)(base + r)*ED + 4*j);
        const float nx = __shfl(uu.x, (lane + 1) & 63, 64);
        const float ny = __shfl(uu.y, (lane + 1) & 63, 64);
        float c10 = fmaxf(b1v + w10*uu.x + w11*uu.y + w12*uu.z, 0.f);
        float c11 = fmaxf(b1v + w10*uu.y + w11*uu.z + w12*uu.w, 0.f);
        float c12 = fmaxf(b1v + w10*uu.z + w11*uu.w + w12*nx  , 0.f);
        float c13 = fmaxf(b1v + w10*uu.w + w11*nx   + w12*ny  , 0.f);
        float c20 = fmaxf(b2v + w20*uu.x + w21*uu.y + w22*uu.z + qp4.x, 0.f);
        float c21 = fmaxf(b2v + w20*uu.y + w21*uu.z + w22*uu.w + qp4.y, 0.f);
        float c22 = fmaxf(b2v + w20*uu.z + w21*uu.w + w22*nx   + qp4.z, 0.f);
        float c23 = fmaxf(b2v + w20*uu.w + w21*nx   + w22*ny   + qp4.w, 0.f);
        if (j == 31) { c12 = 0.f; c13 = 0.f; c22 = 0.f; c23 = 0.f; }   // conv pads
        uint2 v1; v1.x = packbf2(c10, c11); v1.y = packbf2(c12, c13);
        uint2 v2; v2.x = packbf2(c20, c21); v2.y = packbf2(c22, c23);
        *(uint2*)&X[r][2*j]      = v1;
        *(uint2*)&X[r][64 + 2*j] = v2;
    }
    __syncthreads();

    // GEMM: wave quadrant = 32 pairs x 32 taps, K=256
    float4v acc00 = {0.f,0.f,0.f,0.f}, acc01 = {0.f,0.f,0.f,0.f};
    float4v acc10 = {0.f,0.f,0.f,0.f}, acc11 = {0.f,0.f,0.f,0.f};
    const char* Xb = (const char*)&X[0][0];
    #pragma unroll
    for (int kt = 0; kt < 8; ++kt) {
        const short8v a0 = *(const short8v*)(Xb + (mbase + li)*528      + kt*64 + g*16);
        const short8v a1 = *(const short8v*)(Xb + (mbase + 16 + li)*528 + kt*64 + g*16);
        acc00 = __builtin_amdgcn_mfma_f32_16x16x32_bf16(a0, bfr0[kt], acc00, 0, 0, 0);
        acc01 = __builtin_amdgcn_mfma_f32_16x16x32_bf16(a0, bfr1[kt], acc01, 0, 0, 0);
        acc10 = __builtin_amdgcn_mfma_f32_16x16x32_bf16(a1, bfr0[kt], acc10, 0, 0, 0);
        acc11 = __builtin_amdgcn_mfma_f32_16x16x32_bf16(a1, bfr1[kt], acc11, 0, 0, 0);
    }

    // epilogue: per-pair partials over this wave's 32 taps
    #pragma unroll
    for (int mi = 0; mi < 2; ++mi) {
        #pragma unroll
        for (int reg = 0; reg < 4; ++reg) {
            const float a0v = mi ? acc10[reg] : acc00[reg];
            const float a1v = mi ? acc11[reg] : acc01[reg];
            float v = wf0 * fmaxf(a0v + qt0, 0.f) + wf1 * fmaxf(a1v + qt1, 0.f);
            v += __shfl_xor(v, 1, 64);
            v += __shfl_xor(v, 2, 64);
            v += __shfl_xor(v, 4, 64);
            v += __shfl_xor(v, 8, 64);
            if (li == 0) pscore[nhalf][mbase + mi*16 + g*4 + reg] = v;
        }
    }
    __syncthreads();

    if (w == 0) {
        const float d = pscore[0][lane] + pscore[1][lane] + beff - shigh;
        float val = (myuid != 0) ? 1.f / (1.f + __expf(-d)) : 0.f;
        #pragma unroll
        for (int off = 32; off > 0; off >>= 1) val += __shfl_xor(val, off, 64);
        if (lane == 0) ws[WS_PART + bid] = val;
    }
}

// ---------------- Kernel D: final reduce ----------------
__global__ __launch_bounds__(256) void k_reduce(const float* __restrict__ ws, float* __restrict__ out)
{
    __shared__ float sh[4];
    float s = 0.f;
    #pragma unroll
    for (int it = 0; it < GRID_C/256; ++it) s += ws[WS_PART + it*256 + threadIdx.x];
    #pragma unroll
    for (int off = 32; off > 0; off >>= 1) s += __shfl_xor(s, off, 64);
    if ((threadIdx.x & 63) == 0) sh[threadIdx.x >> 6] = s;
    __syncthreads();
    if (threadIdx.x == 0) out[0] = sh[0] + sh[1] + sh[2] + sh[3];
}

extern "C" void kernel_launch(void* const* d_in, const int* in_sizes, int n_in,
                              void* d_out, int out_size, void* d_ws, size_t ws_size,
                              hipStream_t stream)
{
    const float* users    = (const float*)d_in[0];
    const float* top_user = (const float*)d_in[1];
    const float* question = (const float*)d_in[2];
    const int*   uids     = (const int*)d_in[3];
    const float* W1  = (const float*)d_in[4];
    const float* b1  = (const float*)d_in[5];
    const float* W2  = (const float*)d_in[6];
    const float* b2  = (const float*)d_in[7];
    const float* W3  = (const float*)d_in[8];
    const float* b3  = (const float*)d_in[9];
    const float* fw1 = (const float*)d_in[10];
    const float* fb1 = (const float*)d_in[11];
    const float* fw2 = (const float*)d_in[12];
    const float* fb2 = (const float*)d_in[13];
    const float* fw3 = (const float*)d_in[14];
    const float* fb3 = (const float*)d_in[15];
    float* ws  = (float*)d_ws;
    float* out = (float*)d_out;

    hipLaunchKernelGGL(k_prep, dim3(NB + 1), dim3(64), 0, stream,
                       top_user, question, W1, b1, W2, b2, W3, b3,
                       fw1, fb1, fw2, fb2, fw3, fb3, ws);
    hipLaunchKernelGGL(k_pairs, dim3(GRID_C), dim3(256), 0, stream,
                       users, uids, ws, W1, b1, W2, b2);
    hipLaunchKernelGGL(k_reduce, dim3(1), dim3(256), 0, stream, ws, out);
}

// Round 6
// 36.540 us; speedup vs baseline: 2.4406x; 1.1645x over previous
//
#include <hip/hip_runtime.h>
#include <hip/hip_bf16.h>

typedef __attribute__((ext_vector_type(8))) short short8v;
typedef __attribute__((ext_vector_type(4))) float float4v;

// Problem constants
#define NB 64
#define NN 2048
#define ED 128
#define GRID_P 1024           // k_pairs blocks, 2 chunks of 64 pairs each

// workspace layout (float offsets)
#define WS_WEFF  0                  // 64 (weff[63], [63]=0)
#define WS_BEFF  64                 // 1
#define WS_SHIGH 128                // 64
#define WS_QTERM 192                // 64*64  (qterm + b3 folded)
#define WS_QPRE  (192+4096)         // 64*128
#define WS_PART  (WS_QPRE+8192)     // 1024
#define WS_BPACK (WS_PART+2048)     // bf16[16384] = 4096 floats, 16B aligned

static __device__ __forceinline__ unsigned int packbf2(float a, float b) {
    __hip_bfloat162 h = __float22bfloat162_rn(make_float2(a, b));
    return *(unsigned int*)&h;
}

// ---------------- Kernel P ----------------
// blocks 0..NB-1: per-batch precompute. block NB: weff/beff. blocks NB..NB+7: bpack slice kt=blk-NB.
__global__ __launch_bounds__(64) void k_prep(
    const float* __restrict__ top_user, const float* __restrict__ question,
    const float* __restrict__ W1, const float* __restrict__ b1,
    const float* __restrict__ W2, const float* __restrict__ b2,
    const float* __restrict__ W3, const float* __restrict__ b3,
    const float* __restrict__ fw1, const float* __restrict__ fb1,
    const float* __restrict__ fw2, const float* __restrict__ fb2,
    const float* __restrict__ fw3, const float* __restrict__ fb3,
    float* __restrict__ ws)
{
    const int lane = threadIdx.x;
    const int blk = blockIdx.x;
    __shared__ float g[16];
    __shared__ float w3s[192];
    w3s[lane] = W3[lane];
    w3s[64 + lane] = W3[64 + lane];
    w3s[128 + lane] = W3[128 + lane];
    if (lane < 16) {
        float s = 0.f;
        #pragma unroll
        for (int i = 0; i < 16; ++i) s += fw3[i] * fw2[i*16 + lane];
        g[lane] = s;
    }
    __syncthreads();

    if (blk >= NB) {
        const int kt = blk - NB;
        if (kt == 0) {
            // weff / beff
            float wv = 0.f;
            if (lane < 63) {
                #pragma unroll
                for (int k = 0; k < 16; ++k) wv += g[k] * fw1[k*63 + lane];
            }
            ws[WS_WEFF + lane] = wv;
            if (lane == 0) {
                float be = fb3[0];
                #pragma unroll
                for (int i = 0; i < 16; ++i) be += fw3[i] * fb2[i];
                #pragma unroll
                for (int k = 0; k < 16; ++k) be += g[k] * fb1[k];
                ws[WS_BEFF] = be;
            }
        }
        // bpack slice kt: bp[((kt*4+nt)*64+lane)*8+idx] = B[kt*32+8*(lane>>4)+idx][nt*16+(lane&15)]
        __hip_bfloat16* bp = (__hip_bfloat16*)(ws + WS_BPACK);
        const int g8 = (lane >> 4) * 8, li = lane & 15;
        #pragma unroll
        for (int nt = 0; nt < 4; ++nt) {
            const int tt = nt*16 + li;
            #pragma unroll
            for (int idx = 0; idx < 8; ++idx) {
                const int k = kt*32 + g8 + idx;
                const int j = k - tt;
                const int k2 = k - 128, j2 = k2 - tt;
                const bool v0 = (tt < 63) && (k < 126) && (j >= 0) && (j < 64);
                const bool v2 = (tt < 63) && (k2 >= 0) && (k2 < 126) && (j2 >= 0) && (j2 < 64);
                float v = (v0 ? w3s[j & 63] : 0.f) + (v2 ? w3s[128 + (j2 & 63)] : 0.f);
                bp[((kt*4 + nt)*64 + lane)*8 + idx] = __float2bfloat16(v);
            }
        }
        return;
    }

    // per-batch precompute (weff/beff recomputed locally)
    float wv = 0.f;
    if (lane < 63) {
        #pragma unroll
        for (int k = 0; k < 16; ++k) wv += g[k] * fw1[k*63 + lane];
    }
    float be = fb3[0];
    #pragma unroll
    for (int i = 0; i < 16; ++i) be += fw3[i] * fb2[i];
    #pragma unroll
    for (int k = 0; k < 16; ++k) be += g[k] * fb1[k];

    __shared__ float q[132], tu[132], c1q[128], qt[64];
    __shared__ float4 D4[64];
    const int b = blk;
    ((float2*)q)[lane]  = ((const float2*)(question + b*ED))[lane];
    ((float2*)tu)[lane] = ((const float2*)(top_user + b*ED))[lane];
    if (lane == 63) {
        q[128]=0.f; q[129]=0.f; q[130]=0.f; q[131]=0.f;
        tu[128]=0.f; tu[129]=0.f; tu[130]=0.f; tu[131]=0.f;
    }
    __syncthreads();
    const float w10=W1[0], w11=W1[1], w12=W1[2];
    const float w20=W2[0], w21=W2[1], w22=W2[2];
    const float w23=W2[3], w24=W2[4], w25=W2[5];
    const float b1v=b1[0], b2v=b2[0], b3v=b3[0];
    const int i = 2*lane;
    float c1qa = fmaxf(b1v + w10*q[i]   + w11*q[i+1] + w12*q[i+2], 0.f);
    float c1qb = fmaxf(b1v + w10*q[i+1] + w11*q[i+2] + w12*q[i+3], 0.f);
    float qpa  = w23*q[i]   + w24*q[i+1] + w25*q[i+2];
    float qpb  = w23*q[i+1] + w24*q[i+2] + w25*q[i+3];
    float c1ta = fmaxf(b1v + w10*tu[i]   + w11*tu[i+1] + w12*tu[i+2], 0.f);
    float c1tb = fmaxf(b1v + w10*tu[i+1] + w11*tu[i+2] + w12*tu[i+3], 0.f);
    float c2a  = fmaxf(b2v + w20*tu[i]   + w21*tu[i+1] + w22*tu[i+2] + qpa, 0.f);
    float c2b  = fmaxf(b2v + w20*tu[i+1] + w21*tu[i+2] + w22*tu[i+3] + qpb, 0.f);
    if (lane == 63) { c1qa=0.f; c1qb=0.f; qpa=0.f; qpb=0.f; c1ta=0.f; c1tb=0.f; c2a=0.f; c2b=0.f; }
    c1q[i] = c1qa; c1q[i+1] = c1qb;
    ws[WS_QPRE + b*128 + i]     = qpa;
    ws[WS_QPRE + b*128 + i + 1] = qpb;
    D4[lane] = make_float4(c1ta, c2a, c1tb, c2b);
    __syncthreads();
    float qtv = 0.f;
    if (lane < 63) {
        #pragma unroll
        for (int j = 0; j < 64; ++j) qtv += w3s[64 + j] * c1q[lane + j];
    }
    qt[lane] = qtv;
    ws[WS_QTERM + b*64 + lane] = qtv + b3v;   // fold b3 for GEMM epilogue
    __syncthreads();
    float acc0 = b3v + qt[lane];
    float acc1 = 0.f;
    const float2* D2 = (const float2*)D4;
    #pragma unroll
    for (int j = 0; j < 64; ++j) {
        const float2 d = D2[lane + j];
        acc0 = fmaf(w3s[j],       d.x, acc0);
        acc1 = fmaf(w3s[128 + j], d.y, acc1);
    }
    float v = wv * fmaxf(acc0 + acc1, 0.f);
    #pragma unroll
    for (int off = 32; off > 0; off >>= 1) v += __shfl_xor(v, off, 64);
    if (lane == 0) ws[WS_SHIGH + b] = v + be;
}

// ---------------- Kernel C: 2 chunks of 64 pairs per block, MFMA GEMM ----------------
__global__ __launch_bounds__(256, 4) void k_pairs(
    const float* __restrict__ users, const int* __restrict__ uids,
    float* __restrict__ ws,
    const float* __restrict__ W1, const float* __restrict__ b1,
    const float* __restrict__ W2, const float* __restrict__ b2)
{
    __shared__ __align__(16) unsigned int X[64][132];   // 33792 B
    __shared__ float pscore[2][2][64];                  // [chunk][nhalf][pair]
    const int tid = threadIdx.x;
    const int w = tid >> 6, lane = tid & 63;
    const int bid = blockIdx.x;
    const int b = bid >> 4;            // 16 blocks per batch
    const int cpair = bid & 15;
    const int base0 = b*NN + cpair*128;
    const int base1 = base0 + 64;

    // prefix property: uids nonzero exactly for n < length
    if (uids[base0] == 0) {
        if (tid == 0) ws[WS_PART + bid] = 0.f;
        return;
    }
    const bool act1 = (uids[base1] != 0);

    const int g = lane >> 4, li = lane & 15;
    const int nhalf = w >> 1;            // tap half
    const int mbase = (w & 1) * 32;      // pair half

    // uid masks early (w0 only uses them at the end)
    const int myuid0 = (w == 0) ? uids[base0 + lane] : 1;
    const int myuid1 = (w == 0) ? uids[base1 + lane] : 1;

    // B fragments from global (32KB, L2/L3-resident, shared by all blocks)
    const __hip_bfloat16* bp = (const __hip_bfloat16*)(ws + WS_BPACK);
    short8v bfr0[8], bfr1[8];
    #pragma unroll
    for (int kt = 0; kt < 8; ++kt) {
        bfr0[kt] = *(const short8v*)(bp + (((kt*4 + nhalf*2 + 0)*64 + lane) << 3));
        bfr1[kt] = *(const short8v*)(bp + (((kt*4 + nhalf*2 + 1)*64 + lane) << 3));
    }

    const int t0 = nhalf*32 + li, t1 = t0 + 16;
    const float wf0 = ws[WS_WEFF + t0], wf1 = ws[WS_WEFF + t1];
    const float qt0 = ws[WS_QTERM + b*64 + t0], qt1 = ws[WS_QTERM + b*64 + t1];
    const float shigh = ws[WS_SHIGH + b], beff = ws[WS_BEFF];

    const float w10=W1[0], w11=W1[1], w12=W1[2];
    const float w20=W2[0], w21=W2[1], w22=W2[2];
    const float b1v=b1[0], b2v=b2[0];
    const int h = lane >> 5, j = lane & 31;
    const float4 qp4 = *(const float4*)&ws[WS_QPRE + b*128 + 4*j];
    const int r0 = w * 16;

    // X-prep from a register-staged set of 8 float4 (2 rows/pass)
    auto prep = [&](const float4* ur) {
        #pragma unroll
        for (int pass = 0; pass < 8; ++pass) {
            const int r = r0 + pass*2 + h;
            const float4 uu = ur[pass];
            const float nx = __shfl(uu.x, (lane + 1) & 63, 64);
            const float ny = __shfl(uu.y, (lane + 1) & 63, 64);
            float c10 = fmaxf(b1v + w10*uu.x + w11*uu.y + w12*uu.z, 0.f);
            float c11 = fmaxf(b1v + w10*uu.y + w11*uu.z + w12*uu.w, 0.f);
            float c12 = fmaxf(b1v + w10*uu.z + w11*uu.w + w12*nx  , 0.f);
            float c13 = fmaxf(b1v + w10*uu.w + w11*nx   + w12*ny  , 0.f);
            float c20 = fmaxf(b2v + w20*uu.x + w21*uu.y + w22*uu.z + qp4.x, 0.f);
            float c21 = fmaxf(b2v + w20*uu.y + w21*uu.z + w22*uu.w + qp4.y, 0.f);
            float c22 = fmaxf(b2v + w20*uu.z + w21*uu.w + w22*nx   + qp4.z, 0.f);
            float c23 = fmaxf(b2v + w20*uu.w + w21*nx   + w22*ny   + qp4.w, 0.f);
            if (j == 31) { c12 = 0.f; c13 = 0.f; c22 = 0.f; c23 = 0.f; }   // conv pads
            uint2 v1; v1.x = packbf2(c10, c11); v1.y = packbf2(c12, c13);
            uint2 v2; v2.x = packbf2(c20, c21); v2.y = packbf2(c22, c23);
            *(uint2*)&X[r][2*j]      = v1;
            *(uint2*)&X[r][64 + 2*j] = v2;
        }
    };

    // GEMM + epilogue into pscore[c]
    auto gemm_ep = [&](int c) {
        float4v acc00 = {0.f,0.f,0.f,0.f}, acc01 = {0.f,0.f,0.f,0.f};
        float4v acc10 = {0.f,0.f,0.f,0.f}, acc11 = {0.f,0.f,0.f,0.f};
        const char* Xb = (const char*)&X[0][0];
        #pragma unroll
        for (int kt = 0; kt < 8; ++kt) {
            const short8v a0 = *(const short8v*)(Xb + (mbase + li)*528      + kt*64 + g*16);
            const short8v a1 = *(const short8v*)(Xb + (mbase + 16 + li)*528 + kt*64 + g*16);
            acc00 = __builtin_amdgcn_mfma_f32_16x16x32_bf16(a0, bfr0[kt], acc00, 0, 0, 0);
            acc01 = __builtin_amdgcn_mfma_f32_16x16x32_bf16(a0, bfr1[kt], acc01, 0, 0, 0);
            acc10 = __builtin_amdgcn_mfma_f32_16x16x32_bf16(a1, bfr0[kt], acc10, 0, 0, 0);
            acc11 = __builtin_amdgcn_mfma_f32_16x16x32_bf16(a1, bfr1[kt], acc11, 0, 0, 0);
        }
        #pragma unroll
        for (int mi = 0; mi < 2; ++mi) {
            #pragma unroll
            for (int reg = 0; reg < 4; ++reg) {
                const float a0v = mi ? acc10[reg] : acc00[reg];
                const float a1v = mi ? acc11[reg] : acc01[reg];
                float v = wf0 * fmaxf(a0v + qt0, 0.f) + wf1 * fmaxf(a1v + qt1, 0.f);
                v += __shfl_xor(v, 1, 64);
                v += __shfl_xor(v, 2, 64);
                v += __shfl_xor(v, 4, 64);
                v += __shfl_xor(v, 8, 64);
                if (li == 0) pscore[c][nhalf][mbase + mi*16 + g*4 + reg] = v;
            }
        }
    };

    // ---- chunk 0 loads + prep ----
    float4 u0r[8];
    #pragma unroll
    for (int pass = 0; pass < 8; ++pass) {
        const int r = r0 + pass*2 + h;
        u0r[pass] = *(const float4*)(users + (size_t)(base0 + r)*ED + 4*j);
    }
    prep(u0r);
    __syncthreads();

    // issue chunk-1 loads before chunk-0 GEMM (latency hides under MFMA)
    float4 u1r[8];
    if (act1) {
        #pragma unroll
        for (int pass = 0; pass < 8; ++pass) {
            const int r = r0 + pass*2 + h;
            u1r[pass] = *(const float4*)(users + (size_t)(base1 + r)*ED + 4*j);
        }
    }

    gemm_ep(0);
    __syncthreads();

    if (act1) prep(u1r);
    __syncthreads();
    if (act1) gemm_ep(1);
    __syncthreads();

    if (w == 0) {
        const float d0 = pscore[0][0][lane] + pscore[0][1][lane] + beff - shigh;
        float val = (myuid0 != 0) ? 1.f / (1.f + __expf(-d0)) : 0.f;
        if (act1) {
            const float d1 = pscore[1][0][lane] + pscore[1][1][lane] + beff - shigh;
            val += (myuid1 != 0) ? 1.f / (1.f + __expf(-d1)) : 0.f;
        }
        #pragma unroll
        for (int off = 32; off > 0; off >>= 1) val += __shfl_xor(val, off, 64);
        if (lane == 0) ws[WS_PART + bid] = val;
    }
}

// ---------------- Kernel D: final reduce ----------------
__global__ __launch_bounds__(256) void k_reduce(const float* __restrict__ ws, float* __restrict__ out)
{
    __shared__ float sh[4];
    float s = 0.f;
    #pragma unroll
    for (int it = 0; it < GRID_P/256; ++it) s += ws[WS_PART + it*256 + threadIdx.x];
    #pragma unroll
    for (int off = 32; off > 0; off >>= 1) s += __shfl_xor(s, off, 64);
    if ((threadIdx.x & 63) == 0) sh[threadIdx.x >> 6] = s;
    __syncthreads();
    if (threadIdx.x == 0) out[0] = sh[0] + sh[1] + sh[2] + sh[3];
}

extern "C" void kernel_launch(void* const* d_in, const int* in_sizes, int n_in,
                              void* d_out, int out_size, void* d_ws, size_t ws_size,
                              hipStream_t stream)
{
    const float* users    = (const float*)d_in[0];
    const float* top_user = (const float*)d_in[1];
    const float* question = (const float*)d_in[2];
    const int*   uids     = (const int*)d_in[3];
    const float* W1  = (const float*)d_in[4];
    const float* b1  = (const float*)d_in[5];
    const float* W2  = (const float*)d_in[6];
    const float* b2  = (const float*)d_in[7];
    const float* W3  = (const float*)d_in[8];
    const float* b3  = (const float*)d_in[9];
    const float* fw1 = (const float*)d_in[10];
    const float* fb1 = (const float*)d_in[11];
    const float* fw2 = (const float*)d_in[12];
    const float* fb2 = (const float*)d_in[13];
    const float* fw3 = (const float*)d_in[14];
    const float* fb3 = (const float*)d_in[15];
    float* ws  = (float*)d_ws;
    float* out = (float*)d_out;

    hipLaunchKernelGGL(k_prep, dim3(NB + 8), dim3(64), 0, stream,
                       top_user, question, W1, b1, W2, b2, W3, b3,
                       fw1, fb1, fw2, fb2, fw3, fb3, ws);
    hipLaunchKernelGGL(k_pairs, dim3(GRID_P), dim3(256), 0, stream,
                       users, uids, ws, W1, b1, W2, b2);
    hipLaunchKernelGGL(k_reduce, dim3(1), dim3(256), 0, stream, ws, out);
}

// Round 7
// 36.130 us; speedup vs baseline: 2.4684x; 1.0114x over previous
//
#include <hip/hip_runtime.h>
#include <hip/hip_bf16.h>

typedef __attribute__((ext_vector_type(8))) short short8v;
typedef __attribute__((ext_vector_type(4))) float float4v;

// Problem constants
#define NB 64
#define NN 2048
#define ED 128
#define GRID_P 1024           // k_pairs blocks, 2 chunks of 64 pairs each

// workspace layout (float offsets)
#define WS_WEFF  0                  // 64 (weff[63], [63]=0)
#define WS_BEFF  64                 // 1
#define WS_SHIGH 128                // 64
#define WS_QTERM 192                // 64*64  (qterm + b3 folded)
#define WS_QPRE  (192+4096)         // 64*128
#define WS_BPACK (192+4096+8192)    // bf16[16384] = 4096 floats, 16B aligned

static __device__ __forceinline__ unsigned int packbf2(float a, float b) {
    __hip_bfloat162 h = __float22bfloat162_rn(make_float2(a, b));
    return *(unsigned int*)&h;
}

// ---------------- Kernel P ----------------
// blocks 0..NB-1: per-batch precompute. blocks NB..NB+7: bpack slice kt=blk-NB (blk NB also weff/beff + out reset).
__global__ __launch_bounds__(64) void k_prep(
    const float* __restrict__ top_user, const float* __restrict__ question,
    const float* __restrict__ W1, const float* __restrict__ b1,
    const float* __restrict__ W2, const float* __restrict__ b2,
    const float* __restrict__ W3, const float* __restrict__ b3,
    const float* __restrict__ fw1, const float* __restrict__ fb1,
    const float* __restrict__ fw2, const float* __restrict__ fb2,
    const float* __restrict__ fw3, const float* __restrict__ fb3,
    float* __restrict__ ws, float* __restrict__ out)
{
    const int lane = threadIdx.x;
    const int blk = blockIdx.x;
    __shared__ float g[16];
    __shared__ float w3s[192];
    w3s[lane] = W3[lane];
    w3s[64 + lane] = W3[64 + lane];
    w3s[128 + lane] = W3[128 + lane];
    if (lane < 16) {
        float s = 0.f;
        #pragma unroll
        for (int i = 0; i < 16; ++i) s += fw3[i] * fw2[i*16 + lane];
        g[lane] = s;
    }
    __syncthreads();

    if (blk >= NB) {
        const int kt = blk - NB;
        if (kt == 0) {
            // zero the output accumulator for this launch (stream-ordered before k_pairs)
            if (lane == 0) out[0] = 0.f;
            // weff / beff
            float wv = 0.f;
            if (lane < 63) {
                #pragma unroll
                for (int k = 0; k < 16; ++k) wv += g[k] * fw1[k*63 + lane];
            }
            ws[WS_WEFF + lane] = wv;
            if (lane == 0) {
                float be = fb3[0];
                #pragma unroll
                for (int i = 0; i < 16; ++i) be += fw3[i] * fb2[i];
                #pragma unroll
                for (int k = 0; k < 16; ++k) be += g[k] * fb1[k];
                ws[WS_BEFF] = be;
            }
        }
        // bpack slice kt: bp[((kt*4+nt)*64+lane)*8+idx] = B[kt*32+8*(lane>>4)+idx][nt*16+(lane&15)]
        __hip_bfloat16* bp = (__hip_bfloat16*)(ws + WS_BPACK);
        const int g8 = (lane >> 4) * 8, li = lane & 15;
        #pragma unroll
        for (int nt = 0; nt < 4; ++nt) {
            const int tt = nt*16 + li;
            #pragma unroll
            for (int idx = 0; idx < 8; ++idx) {
                const int k = kt*32 + g8 + idx;
                const int j = k - tt;
                const int k2 = k - 128, j2 = k2 - tt;
                const bool v0 = (tt < 63) && (k < 126) && (j >= 0) && (j < 64);
                const bool v2 = (tt < 63) && (k2 >= 0) && (k2 < 126) && (j2 >= 0) && (j2 < 64);
                float v = (v0 ? w3s[j & 63] : 0.f) + (v2 ? w3s[128 + (j2 & 63)] : 0.f);
                bp[((kt*4 + nt)*64 + lane)*8 + idx] = __float2bfloat16(v);
            }
        }
        return;
    }

    // per-batch precompute (weff/beff recomputed locally)
    float wv = 0.f;
    if (lane < 63) {
        #pragma unroll
        for (int k = 0; k < 16; ++k) wv += g[k] * fw1[k*63 + lane];
    }
    float be = fb3[0];
    #pragma unroll
    for (int i = 0; i < 16; ++i) be += fw3[i] * fb2[i];
    #pragma unroll
    for (int k = 0; k < 16; ++k) be += g[k] * fb1[k];

    __shared__ float q[132], tu[132], c1q[128], qt[64];
    __shared__ float4 D4[64];
    const int b = blk;
    ((float2*)q)[lane]  = ((const float2*)(question + b*ED))[lane];
    ((float2*)tu)[lane] = ((const float2*)(top_user + b*ED))[lane];
    if (lane == 63) {
        q[128]=0.f; q[129]=0.f; q[130]=0.f; q[131]=0.f;
        tu[128]=0.f; tu[129]=0.f; tu[130]=0.f; tu[131]=0.f;
    }
    __syncthreads();
    const float w10=W1[0], w11=W1[1], w12=W1[2];
    const float w20=W2[0], w21=W2[1], w22=W2[2];
    const float w23=W2[3], w24=W2[4], w25=W2[5];
    const float b1v=b1[0], b2v=b2[0], b3v=b3[0];
    const int i = 2*lane;
    float c1qa = fmaxf(b1v + w10*q[i]   + w11*q[i+1] + w12*q[i+2], 0.f);
    float c1qb = fmaxf(b1v + w10*q[i+1] + w11*q[i+2] + w12*q[i+3], 0.f);
    float qpa  = w23*q[i]   + w24*q[i+1] + w25*q[i+2];
    float qpb  = w23*q[i+1] + w24*q[i+2] + w25*q[i+3];
    float c1ta = fmaxf(b1v + w10*tu[i]   + w11*tu[i+1] + w12*tu[i+2], 0.f);
    float c1tb = fmaxf(b1v + w10*tu[i+1] + w11*tu[i+2] + w12*tu[i+3], 0.f);
    float c2a  = fmaxf(b2v + w20*tu[i]   + w21*tu[i+1] + w22*tu[i+2] + qpa, 0.f);
    float c2b  = fmaxf(b2v + w20*tu[i+1] + w21*tu[i+2] + w22*tu[i+3] + qpb, 0.f);
    if (lane == 63) { c1qa=0.f; c1qb=0.f; qpa=0.f; qpb=0.f; c1ta=0.f; c1tb=0.f; c2a=0.f; c2b=0.f; }
    c1q[i] = c1qa; c1q[i+1] = c1qb;
    ws[WS_QPRE + b*128 + i]     = qpa;
    ws[WS_QPRE + b*128 + i + 1] = qpb;
    D4[lane] = make_float4(c1ta, c2a, c1tb, c2b);
    __syncthreads();
    float qtv = 0.f;
    if (lane < 63) {
        #pragma unroll
        for (int j = 0; j < 64; ++j) qtv += w3s[64 + j] * c1q[lane + j];
    }
    qt[lane] = qtv;
    ws[WS_QTERM + b*64 + lane] = qtv + b3v;   // fold b3 for GEMM epilogue
    __syncthreads();
    float acc0 = b3v + qt[lane];
    float acc1 = 0.f;
    const float2* D2 = (const float2*)D4;
    #pragma unroll
    for (int j = 0; j < 64; ++j) {
        const float2 d = D2[lane + j];
        acc0 = fmaf(w3s[j],       d.x, acc0);
        acc1 = fmaf(w3s[128 + j], d.y, acc1);
    }
    float v = wv * fmaxf(acc0 + acc1, 0.f);
    #pragma unroll
    for (int off = 32; off > 0; off >>= 1) v += __shfl_xor(v, off, 64);
    if (lane == 0) ws[WS_SHIGH + b] = v + be;
}

// ---------------- Kernel C: 2 chunks of 64 pairs per block, MFMA GEMM, atomic final reduce ----------------
__global__ __launch_bounds__(256, 4) void k_pairs(
    const float* __restrict__ users, const int* __restrict__ uids,
    float* __restrict__ ws, float* __restrict__ out,
    const float* __restrict__ W1, const float* __restrict__ b1,
    const float* __restrict__ W2, const float* __restrict__ b2)
{
    __shared__ __align__(16) unsigned int X[64][132];   // 33792 B
    __shared__ float pscore[2][2][64];                  // [chunk][nhalf][pair]
    const int tid = threadIdx.x;
    const int w = tid >> 6, lane = tid & 63;
    const int bid = blockIdx.x;
    const int b = bid >> 4;            // 16 blocks per batch
    const int cpair = bid & 15;
    const int base0 = b*NN + cpair*128;
    const int base1 = base0 + 64;

    // prefix property: uids nonzero exactly for n < length
    if (uids[base0] == 0) return;
    const bool act1 = (uids[base1] != 0);

    const int g = lane >> 4, li = lane & 15;
    const int nhalf = w >> 1;            // tap half
    const int mbase = (w & 1) * 32;      // pair half

    // uid masks early
    const int myuid0 = (w == 0) ? uids[base0 + lane] : 1;
    const int myuid1 = (w == 0) ? uids[base1 + lane] : 1;

    const float w10=W1[0], w11=W1[1], w12=W1[2];
    const float w20=W2[0], w21=W2[1], w22=W2[2];
    const float b1v=b1[0], b2v=b2[0];
    const int h = lane >> 5, j = lane & 31;
    const int r0 = w * 16;

    // ---- issue ALL global loads up front: both chunks' users rows ----
    float4 u0r[8], u1r[8];
    #pragma unroll
    for (int pass = 0; pass < 8; ++pass) {
        const int r = r0 + pass*2 + h;
        u0r[pass] = *(const float4*)(users + (size_t)(base0 + r)*ED + 4*j);
    }
    if (act1) {
        #pragma unroll
        for (int pass = 0; pass < 8; ++pass) {
            const int r = r0 + pass*2 + h;
            u1r[pass] = *(const float4*)(users + (size_t)(base1 + r)*ED + 4*j);
        }
    }

    // B fragments from global (32KB, L2/L3-resident, shared by all blocks)
    const __hip_bfloat16* bp = (const __hip_bfloat16*)(ws + WS_BPACK);
    short8v bfr0[8], bfr1[8];
    #pragma unroll
    for (int kt = 0; kt < 8; ++kt) {
        bfr0[kt] = *(const short8v*)(bp + (((kt*4 + nhalf*2 + 0)*64 + lane) << 3));
        bfr1[kt] = *(const short8v*)(bp + (((kt*4 + nhalf*2 + 1)*64 + lane) << 3));
    }

    const int t0 = nhalf*32 + li, t1 = t0 + 16;
    const float wf0 = ws[WS_WEFF + t0], wf1 = ws[WS_WEFF + t1];
    const float qt0 = ws[WS_QTERM + b*64 + t0], qt1 = ws[WS_QTERM + b*64 + t1];
    const float shigh = ws[WS_SHIGH + b], beff = ws[WS_BEFF];
    const float4 qp4 = *(const float4*)&ws[WS_QPRE + b*128 + 4*j];

    // X-prep from a register-staged set of 8 float4 (2 rows/pass)
    auto prep = [&](const float4* ur) {
        #pragma unroll
        for (int pass = 0; pass < 8; ++pass) {
            const int r = r0 + pass*2 + h;
            const float4 uu = ur[pass];
            const float nx = __shfl(uu.x, (lane + 1) & 63, 64);
            const float ny = __shfl(uu.y, (lane + 1) & 63, 64);
            float c10 = fmaxf(b1v + w10*uu.x + w11*uu.y + w12*uu.z, 0.f);
            float c11 = fmaxf(b1v + w10*uu.y + w11*uu.z + w12*uu.w, 0.f);
            float c12 = fmaxf(b1v + w10*uu.z + w11*uu.w + w12*nx  , 0.f);
            float c13 = fmaxf(b1v + w10*uu.w + w11*nx   + w12*ny  , 0.f);
            float c20 = fmaxf(b2v + w20*uu.x + w21*uu.y + w22*uu.z + qp4.x, 0.f);
            float c21 = fmaxf(b2v + w20*uu.y + w21*uu.z + w22*uu.w + qp4.y, 0.f);
            float c22 = fmaxf(b2v + w20*uu.z + w21*uu.w + w22*nx   + qp4.z, 0.f);
            float c23 = fmaxf(b2v + w20*uu.w + w21*nx   + w22*ny   + qp4.w, 0.f);
            if (j == 31) { c12 = 0.f; c13 = 0.f; c22 = 0.f; c23 = 0.f; }   // conv pads
            uint2 v1; v1.x = packbf2(c10, c11); v1.y = packbf2(c12, c13);
            uint2 v2; v2.x = packbf2(c20, c21); v2.y = packbf2(c22, c23);
            *(uint2*)&X[r][2*j]      = v1;
            *(uint2*)&X[r][64 + 2*j] = v2;
        }
    };

    // GEMM + epilogue into pscore[c]
    auto gemm_ep = [&](int c) {
        float4v acc00 = {0.f,0.f,0.f,0.f}, acc01 = {0.f,0.f,0.f,0.f};
        float4v acc10 = {0.f,0.f,0.f,0.f}, acc11 = {0.f,0.f,0.f,0.f};
        const char* Xb = (const char*)&X[0][0];
        #pragma unroll
        for (int kt = 0; kt < 8; ++kt) {
            const short8v a0 = *(const short8v*)(Xb + (mbase + li)*528      + kt*64 + g*16);
            const short8v a1 = *(const short8v*)(Xb + (mbase + 16 + li)*528 + kt*64 + g*16);
            acc00 = __builtin_amdgcn_mfma_f32_16x16x32_bf16(a0, bfr0[kt], acc00, 0, 0, 0);
            acc01 = __builtin_amdgcn_mfma_f32_16x16x32_bf16(a0, bfr1[kt], acc01, 0, 0, 0);
            acc10 = __builtin_amdgcn_mfma_f32_16x16x32_bf16(a1, bfr0[kt], acc10, 0, 0, 0);
            acc11 = __builtin_amdgcn_mfma_f32_16x16x32_bf16(a1, bfr1[kt], acc11, 0, 0, 0);
        }
        #pragma unroll
        for (int mi = 0; mi < 2; ++mi) {
            #pragma unroll
            for (int reg = 0; reg < 4; ++reg) {
                const float a0v = mi ? acc10[reg] : acc00[reg];
                const float a1v = mi ? acc11[reg] : acc01[reg];
                float v = wf0 * fmaxf(a0v + qt0, 0.f) + wf1 * fmaxf(a1v + qt1, 0.f);
                v += __shfl_xor(v, 1, 64);
                v += __shfl_xor(v, 2, 64);
                v += __shfl_xor(v, 4, 64);
                v += __shfl_xor(v, 8, 64);
                if (li == 0) pscore[c][nhalf][mbase + mi*16 + g*4 + reg] = v;
            }
        }
    };

    prep(u0r);
    __syncthreads();
    gemm_ep(0);
    __syncthreads();
    if (act1) prep(u1r);
    __syncthreads();
    if (act1) gemm_ep(1);
    __syncthreads();

    if (w == 0) {
        const float d0 = pscore[0][0][lane] + pscore[0][1][lane] + beff - shigh;
        float val = (myuid0 != 0) ? 1.f / (1.f + __expf(-d0)) : 0.f;
        if (act1) {
            const float d1 = pscore[1][0][lane] + pscore[1][1][lane] + beff - shigh;
            val += (myuid1 != 0) ? 1.f / (1.f + __expf(-d1)) : 0.f;
        }
        #pragma unroll
        for (int off = 32; off > 0; off >>= 1) val += __shfl_xor(val, off, 64);
        if (lane == 0) atomicAdd(out, val);   // device-scope, no fence needed
    }
}

extern "C" void kernel_launch(void* const* d_in, const int* in_sizes, int n_in,
                              void* d_out, int out_size, void* d_ws, size_t ws_size,
                              hipStream_t stream)
{
    const float* users    = (const float*)d_in[0];
    const float* top_user = (const float*)d_in[1];
    const float* question = (const float*)d_in[2];
    const int*   uids     = (const int*)d_in[3];
    const float* W1  = (const float*)d_in[4];
    const float* b1  = (const float*)d_in[5];
    const float* W2  = (const float*)d_in[6];
    const float* b2  = (const float*)d_in[7];
    const float* W3  = (const float*)d_in[8];
    const float* b3  = (const float*)d_in[9];
    const float* fw1 = (const float*)d_in[10];
    const float* fb1 = (const float*)d_in[11];
    const float* fw2 = (const float*)d_in[12];
    const float* fb2 = (const float*)d_in[13];
    const float* fw3 = (const float*)d_in[14];
    const float* fb3 = (const float*)d_in[15];
    float* ws  = (float*)d_ws;
    float* out = (float*)d_out;

    hipLaunchKernelGGL(k_prep, dim3(NB + 8), dim3(64), 0, stream,
                       top_user, question, W1, b1, W2, b2, W3, b3,
                       fw1, fb1, fw2, fb2, fw3, fb3, ws, out);
    hipLaunchKernelGGL(k_pairs, dim3(GRID_P), dim3(256), 0, stream,
                       users, uids, ws, out, W1, b1, W2, b2);
}